// Round 4
// baseline (423.388 us; speedup 1.0000x reference)
//
#include <hip/hip_runtime.h>

#define LQ 5376
#define DM 128
#define NH 16
#define NL 3
#define NP 4
#define DH 8
#define NQH (43008 * 16)

typedef __attribute__((ext_vector_type(8))) short short8;
typedef __attribute__((ext_vector_type(4))) float float4_t;
typedef __attribute__((ext_vector_type(4))) unsigned int uint4_t;

__device__ __forceinline__ unsigned short f2bf(float f) {
    unsigned u = __builtin_bit_cast(unsigned, f);
    unsigned r = (u + 0x7fffu + ((u >> 16) & 1u)) >> 16;
    return (unsigned short)r;
}
__device__ __forceinline__ float bf2f(unsigned short h) {
    return __builtin_bit_cast(float, (unsigned)h << 16);
}

__device__ __forceinline__ void q_to_level(int q, int& l, int& p, int& Hl, int& Wl,
                                           int& wshift) {
    if (q < 4096)      { l = 0; p = q;        Hl = 64; Wl = 64; wshift = 6; }
    else if (q < 5120) { l = 1; p = q - 4096; Hl = 32; Wl = 32; wshift = 5; }
    else               { l = 2; p = q - 5120; Hl = 16; Wl = 16; wshift = 4; }
}

// ---- weights -> [col][k] bf16 (hi/lo only for W_out; W_val plain bf16) ----
__global__ __launch_bounds__(256) void convw_k(const float* __restrict__ Wv,
                                               const float* __restrict__ Wo,
                                               const float* __restrict__ Wa,
                                               const float* __restrict__ Wout,
                                               unsigned short* __restrict__ Wvh,
                                               unsigned short* __restrict__ Woa,
                                               unsigned short* __restrict__ Wouth,
                                               unsigned short* __restrict__ Woutl) {
    int idx = blockIdx.x * 256 + threadIdx.x;
    if (idx >= 832 * 128) return;
    int col = idx >> 7;
    int k   = idx & 127;
    if (col < 128) {
        Wvh[col * 128 + k] = f2bf(Wv[k * 128 + col]);
    } else if (col < 512) {
        int c = col - 128;
        Woa[c * 128 + k] = f2bf(Wo[k * 384 + c]);
    } else if (col < 704) {
        int c = col - 512;
        Woa[(384 + c) * 128 + k] = f2bf(Wa[k * 192 + c]);
    } else {
        int c = col - 704;
        float v = Wout[k * 128 + c];
        unsigned short h = f2bf(v);
        Wouth[c * 128 + k] = h;
        Woutl[c * 128 + k] = f2bf(v - bf2f(h));
    }
}

// ---- (B,128,HW) -> x rows (B*LQ,128) bf16 ----
__global__ __launch_bounds__(256) void transpose_k(const float* __restrict__ fm,
                                                   unsigned short* __restrict__ xh,
                                                   int HW, int qstart) {
    __shared__ float tile[32][33];
    const int p0 = blockIdx.x * 32;
    const int c0 = blockIdx.y * 32;
    const int b  = blockIdx.z;
    const int tx = threadIdx.x;  // 32
    const int ty = threadIdx.y;  // 8
    const float* src = fm + ((size_t)(b * DM + c0)) * HW + p0;
#pragma unroll
    for (int k = 0; k < 32; k += 8)
        tile[ty + k][tx] = src[(size_t)(ty + k) * HW + tx];
    __syncthreads();
    const size_t dbase = ((size_t)(b * LQ + qstart + p0)) * DM + c0;
#pragma unroll
    for (int k = 0; k < 32; k += 8)
        xh[dbase + (size_t)(ty + k) * DM + tx] = f2bf(tile[tx][ty + k]);
}

// ---- value = x @ W_val + b_val (bf16 MFMA), repack to head-major valh ----
// valh layout: [(h*8 + b) * LQ + pos] * 8 channels (bf16), 16 B per (h,b,pos)
__global__ __launch_bounds__(256) void value_proj_mfma(const unsigned short* __restrict__ xh,
                                                       const unsigned short* __restrict__ Wvh,
                                                       const float* __restrict__ b_val,
                                                       unsigned short* __restrict__ valh) {
    __shared__ unsigned short vs[64][136];
    const int t = threadIdx.x;
    const int wv = t >> 6;
    const int lane = t & 63;
    const int m = lane & 15, quad = lane >> 4;
    const int q0 = blockIdx.x * 64 + wv * 16;

    short8 ah[4];
    const size_t arow = (size_t)(q0 + m) * DM;
#pragma unroll
    for (int kk = 0; kk < 4; ++kk)
        ah[kk] = *(const short8*)(xh + arow + kk * 32 + quad * 8);
    float4_t acc[8];
#pragma unroll
    for (int tt = 0; tt < 8; ++tt) acc[tt] = (float4_t)(0.f);
#pragma unroll
    for (int tt = 0; tt < 8; ++tt) {
        const size_t brow = (size_t)(tt * 16 + m) * DM;
#pragma unroll
        for (int kk = 0; kk < 4; ++kk) {
            short8 bh = *(const short8*)(Wvh + brow + kk * 32 + quad * 8);
            acc[tt] = __builtin_amdgcn_mfma_f32_16x16x32_bf16(ah[kk], bh, acc[tt], 0, 0, 0);
        }
    }
#pragma unroll
    for (int tt = 0; tt < 8; ++tt) {
        const int col = tt * 16 + m;
        const float bb = b_val[col];
#pragma unroll
        for (int r = 0; r < 4; ++r)
            vs[wv * 16 + quad * 4 + r][col] = f2bf(acc[tt][r] + bb);
    }
    __syncthreads();

    const int bq = blockIdx.x * 64;        // 64 queries, never spans a batch
    const int b = bq / LQ;
    const int pos0 = bq - b * LQ;
    const int h  = t >> 4;
    const int ql = t & 15;
#pragma unroll
    for (int it = 0; it < 4; ++it) {
        const int qloc = it * 16 + ql;
        uint4_t v = *(const uint4_t*)&vs[qloc][h * 8];
        *(uint4_t*)(valh + ((size_t)(h * 8 + b) * LQ + pos0 + qloc) * 8) = v;
    }
}

// ---- coef kernel: [offs|attn logits] = x @ Woa + bias -> paramT[j][q*16+h] ----
__global__ __launch_bounds__(256) void coef_k(const unsigned short* __restrict__ xh,
                                              const unsigned short* __restrict__ Woa,
                                              const float* __restrict__ b_off,
                                              const float* __restrict__ b_attn,
                                              float* __restrict__ paramT) {
    __shared__ float coef[16][16][37];  // [q][h][0..23 offs, 24..35 logits]
    const int t = threadIdx.x;
    const int wv = t >> 6;
    const int lane = t & 63;
    const int m = lane & 15, quad = lane >> 4;
    const int gq0 = blockIdx.x * 16;

    {
        short8 af[4];
        const size_t arow = (size_t)(gq0 + m) * DM;
#pragma unroll
        for (int kk = 0; kk < 4; ++kk)
            af[kk] = *(const short8*)(xh + arow + kk * 32 + quad * 8);
        float4_t acc[9];
#pragma unroll
        for (int tt = 0; tt < 9; ++tt) acc[tt] = (float4_t)(0.f);
#pragma unroll
        for (int tt = 0; tt < 9; ++tt) {
            const size_t brow = (size_t)((wv * 9 + tt) * 16 + m) * DM;
#pragma unroll
            for (int kk = 0; kk < 4; ++kk) {
                short8 bf = *(const short8*)(Woa + brow + kk * 32 + quad * 8);
                acc[tt] = __builtin_amdgcn_mfma_f32_16x16x32_bf16(af[kk], bf, acc[tt], 0, 0, 0);
            }
        }
#pragma unroll
        for (int tt = 0; tt < 9; ++tt) {
            const int col = (wv * 9 + tt) * 16 + m;
            int hc, jc;
            float bb;
            if (col < 384) { hc = col / 24; jc = col - hc * 24; bb = b_off[col]; }
            else { int cc = col - 384; hc = cc / 12; jc = 24 + cc - hc * 12; bb = b_attn[cc]; }
#pragma unroll
            for (int r = 0; r < 4; ++r)
                coef[quad * 4 + r][hc][jc] = acc[tt][r] + bb;
        }
    }
    __syncthreads();

    // coalesced j-major dump: paramT[j][gq0*16 + t]
    const int qq = t >> 4, hh = t & 15;
#pragma unroll
    for (int j = 0; j < 36; ++j)
        paramT[(size_t)j * NQH + (size_t)gq0 * 16 + t] = coef[qq][hh][j];
}

// ---- sampler: one thread per (q,h); no LDS, no barriers ----
__global__ __launch_bounds__(256, 4) void sample_k(const float* __restrict__ paramT,
                                                   const unsigned short* __restrict__ valh,
                                                   unsigned short* __restrict__ ohb) {
    const int t = threadIdx.x;
    const int gid = blockIdx.x * 256 + t;
    const int h  = gid & 15;
    const int gq = gid >> 4;
    const int b  = gq / LQ;
    const int q  = gq - b * LQ;
    int lq, p, Hq, Wq, wshift;
    q_to_level(q, lq, p, Hq, Wq, wshift);
    const float refx = ((p & (Wq - 1)) + 0.5f) / Wq;
    const float refy = ((p >> wshift) + 0.5f) / Hq;

    float prm[36];
#pragma unroll
    for (int j = 0; j < 36; ++j)
        prm[j] = paramT[(size_t)j * NQH + gid];

    // softmax over logits prm[24..35]
    float mx = -1e30f;
#pragma unroll
    for (int k = 0; k < 12; ++k) mx = fmaxf(mx, prm[24 + k]);
    float s = 0.f;
#pragma unroll
    for (int k = 0; k < 12; ++k) {
        const float e = __expf(prm[24 + k] - mx);
        prm[24 + k] = e;
        s += e;
    }
    const float inv = 1.f / s;

    const unsigned short* vbase = valh + ((size_t)(h * 8 + b) * LQ) * 8;
    float acc[8];
#pragma unroll
    for (int e = 0; e < 8; ++e) acc[e] = 0.f;

#pragma unroll
    for (int l = 0; l < NL; ++l) {
        const int Wl = 64 >> l;
        const int Hl = Wl;
        const int start_l = (l == 0) ? 0 : ((l == 1) ? 4096 : 5120);
        const float fxb = refx * Wl - 0.5f;
        const float fyb = refy * Hl - 0.5f;
#pragma unroll
        for (int pt = 0; pt < NP; ++pt) {
            const float ox = prm[(l * NP + pt) * 2 + 0];
            const float oy = prm[(l * NP + pt) * 2 + 1];
            const float a  = prm[24 + l * NP + pt] * inv;
            const float fx = fxb + ox;
            const float fy = fyb + oy;
            const float x0f = floorf(fx);
            const float y0f = floorf(fy);
            const int x0 = (int)x0f;
            const int y0 = (int)y0f;
            const float fx1 = fx - x0f, fy1 = fy - y0f;
            const float gx0 = (x0 >= 0 && x0 < Wl)      ? (1.f - fx1) : 0.f;
            const float gx1 = (x0 >= -1 && x0 < Wl - 1) ? fx1 : 0.f;
            const float gy0 = (y0 >= 0 && y0 < Hl)      ? (1.f - fy1) : 0.f;
            const float gy1 = (y0 >= -1 && y0 < Hl - 1) ? fy1 : 0.f;
            const int xc0 = min(max(x0, 0), Wl - 1);
            const int xc1 = min(max(x0 + 1, 0), Wl - 1);
            const int yc0 = min(max(y0, 0), Hl - 1);
            const int yc1 = min(max(y0 + 1, 0), Hl - 1);
            const int r0 = start_l + yc0 * Wl;
            const int r1 = start_l + yc1 * Wl;
            const uint4_t v00 = *(const uint4_t*)(vbase + (size_t)(r0 + xc0) * 8);
            const uint4_t v01 = *(const uint4_t*)(vbase + (size_t)(r0 + xc1) * 8);
            const uint4_t v10 = *(const uint4_t*)(vbase + (size_t)(r1 + xc0) * 8);
            const uint4_t v11 = *(const uint4_t*)(vbase + (size_t)(r1 + xc1) * 8);
            const float w00 = gx0 * gy0 * a;
            const float w01 = gx1 * gy0 * a;
            const float w10 = gx0 * gy1 * a;
            const float w11 = gx1 * gy1 * a;
#pragma unroll
            for (int dd = 0; dd < 4; ++dd) {
                acc[dd * 2 + 0] += w00 * __builtin_bit_cast(float, v00[dd] << 16)
                                +  w01 * __builtin_bit_cast(float, v01[dd] << 16)
                                +  w10 * __builtin_bit_cast(float, v10[dd] << 16)
                                +  w11 * __builtin_bit_cast(float, v11[dd] << 16);
                acc[dd * 2 + 1] += w00 * __builtin_bit_cast(float, v00[dd] & 0xffff0000u)
                                +  w01 * __builtin_bit_cast(float, v01[dd] & 0xffff0000u)
                                +  w10 * __builtin_bit_cast(float, v10[dd] & 0xffff0000u)
                                +  w11 * __builtin_bit_cast(float, v11[dd] & 0xffff0000u);
            }
        }
    }

    uint4_t uo;
#pragma unroll
    for (int e = 0; e < 4; ++e)
        uo[e] = (unsigned)f2bf(acc[2 * e]) | ((unsigned)f2bf(acc[2 * e + 1]) << 16);
    *(uint4_t*)(ohb + (size_t)gq * 128 + h * 8) = uo;
}

// ---- out projection: out = ohb @ W_out + b_out (A bf16, B hi/lo), scatter ----
__global__ __launch_bounds__(256) void outproj_k(const unsigned short* __restrict__ ohb,
                                                 const unsigned short* __restrict__ Wouth,
                                                 const unsigned short* __restrict__ Woutl,
                                                 const float* __restrict__ b_out,
                                                 float* __restrict__ out) {
    const int t = threadIdx.x;
    const int wv = t >> 6;
    const int lane = t & 63;
    const int m = lane & 15, quad = lane >> 4;
    const int q0 = blockIdx.x * 64 + wv * 16;

    short8 ah[4];
    const size_t arow = (size_t)(q0 + m) * DM;
#pragma unroll
    for (int kk = 0; kk < 4; ++kk)
        ah[kk] = *(const short8*)(ohb + arow + kk * 32 + quad * 8);

    float4_t acc[8];
#pragma unroll
    for (int tt = 0; tt < 8; ++tt) acc[tt] = (float4_t)(0.f);
#pragma unroll
    for (int tt = 0; tt < 8; ++tt) {
        const size_t brow = (size_t)(tt * 16 + m) * DM;
#pragma unroll
        for (int kk = 0; kk < 4; ++kk) {
            short8 bh = *(const short8*)(Wouth + brow + kk * 32 + quad * 8);
            short8 bl = *(const short8*)(Woutl + brow + kk * 32 + quad * 8);
            acc[tt] = __builtin_amdgcn_mfma_f32_16x16x32_bf16(ah[kk], bh, acc[tt], 0, 0, 0);
            acc[tt] = __builtin_amdgcn_mfma_f32_16x16x32_bf16(ah[kk], bl, acc[tt], 0, 0, 0);
        }
    }

    const int bq = blockIdx.x * 64;
    const int b = bq / LQ;
    const int qs = bq - b * LQ;           // 64-q tile never spans level/batch
    int lq, p0, Hq, Wq, wshift;
    q_to_level(qs, lq, p0, Hq, Wq, wshift);
    const int HW = Hq * Wq;
    const size_t lvl_base[3] = {0, 4194304, 5242880};
    float* obase = out + lvl_base[lq] + (size_t)(b * DM) * HW;
    const int posr = p0 + wv * 16 + quad * 4;
#pragma unroll
    for (int tt = 0; tt < 8; ++tt) {
        const int col = tt * 16 + m;
        const float bb = b_out[col];
        float4_t v;
#pragma unroll
        for (int r = 0; r < 4; ++r) v[r] = acc[tt][r] + bb;
        *(float4_t*)(obase + (size_t)col * HW + posr) = v;
    }
}

extern "C" void kernel_launch(void* const* d_in, const int* in_sizes, int n_in,
                              void* d_out, int out_size, void* d_ws, size_t ws_size,
                              hipStream_t stream) {
    const float* fm1    = (const float*)d_in[0];
    const float* fm2    = (const float*)d_in[1];
    const float* fm3    = (const float*)d_in[2];
    const float* W_off  = (const float*)d_in[3];
    const float* b_off  = (const float*)d_in[4];
    const float* W_attn = (const float*)d_in[5];
    const float* b_attn = (const float*)d_in[6];
    const float* W_val  = (const float*)d_in[7];
    const float* b_val  = (const float*)d_in[8];
    const float* W_out  = (const float*)d_in[9];
    const float* b_out  = (const float*)d_in[10];
    float* out = (float*)d_out;

    const size_t NQ = (size_t)8 * LQ;          // 43008
    unsigned short* xh    = (unsigned short*)d_ws;      // 11.0 MB
    unsigned short* valh  = xh + NQ * DM;               // 11.0 MB (head-major)
    unsigned short* ohb   = valh + NQ * DM;             // 11.0 MB
    unsigned short* Wvh   = ohb + NQ * DM;              // 32 KB
    unsigned short* Woa   = Wvh + 128 * 128;            // 144 KB
    unsigned short* Wouth = Woa + 576 * 128;            // 32 KB
    unsigned short* Woutl = Wouth + 128 * 128;          // 32 KB
    float* paramT = (float*)(Woutl + 128 * 128);        // 99.1 MB

    convw_k<<<416, 256, 0, stream>>>(W_val, W_off, W_attn, W_out,
                                     Wvh, Woa, Wouth, Woutl);

    dim3 tb(32, 8);
    transpose_k<<<dim3(128, 4, 8), tb, 0, stream>>>(fm1, xh, 4096, 0);
    transpose_k<<<dim3(32, 4, 8), tb, 0, stream>>>(fm2, xh, 1024, 4096);
    transpose_k<<<dim3(8, 4, 8), tb, 0, stream>>>(fm3, xh, 256, 5120);

    value_proj_mfma<<<672, 256, 0, stream>>>(xh, Wvh, b_val, valh);

    coef_k<<<2688, 256, 0, stream>>>(xh, Woa, b_off, b_attn, paramT);

    sample_k<<<2688, 256, 0, stream>>>(paramT, valh, ohb);

    outproj_k<<<672, 256, 0, stream>>>(ohb, Wouth, Woutl, b_out, out);
}

// Round 5
// 411.346 us; speedup vs baseline: 1.0293x; 1.0293x over previous
//
#include <hip/hip_runtime.h>

#define LQ 5376
#define DM 128
#define NH 16
#define NL 3
#define NP 4
#define DH 8
#define NQH (43008 * 16)

typedef __attribute__((ext_vector_type(8))) short short8;
typedef __attribute__((ext_vector_type(4))) float float4_t;
typedef __attribute__((ext_vector_type(4))) unsigned int uint4_t;

__device__ __forceinline__ unsigned short f2bf(float f) {
    unsigned u = __builtin_bit_cast(unsigned, f);
    unsigned r = (u + 0x7fffu + ((u >> 16) & 1u)) >> 16;
    return (unsigned short)r;
}
__device__ __forceinline__ float bf2f(unsigned short h) {
    return __builtin_bit_cast(float, (unsigned)h << 16);
}
__device__ __forceinline__ unsigned packh2(float a, float b) {
    unsigned short ua = __builtin_bit_cast(unsigned short, (_Float16)a);
    unsigned short ub = __builtin_bit_cast(unsigned short, (_Float16)b);
    return (unsigned)ua | ((unsigned)ub << 16);
}
__device__ __forceinline__ float unph_lo(unsigned u) {
    return (float)__builtin_bit_cast(_Float16, (unsigned short)(u & 0xffffu));
}
__device__ __forceinline__ float unph_hi(unsigned u) {
    return (float)__builtin_bit_cast(_Float16, (unsigned short)(u >> 16));
}

__device__ __forceinline__ void q_to_level(int q, int& l, int& p, int& Hl, int& Wl,
                                           int& wshift) {
    if (q < 4096)      { l = 0; p = q;        Hl = 64; Wl = 64; wshift = 6; }
    else if (q < 5120) { l = 1; p = q - 4096; Hl = 32; Wl = 32; wshift = 5; }
    else               { l = 2; p = q - 5120; Hl = 16; Wl = 16; wshift = 4; }
}

// ---- weights -> [col][k] bf16 (hi/lo only for W_out; W_val plain bf16) ----
__global__ __launch_bounds__(256) void convw_k(const float* __restrict__ Wv,
                                               const float* __restrict__ Wo,
                                               const float* __restrict__ Wa,
                                               const float* __restrict__ Wout,
                                               unsigned short* __restrict__ Wvh,
                                               unsigned short* __restrict__ Woa,
                                               unsigned short* __restrict__ Wouth,
                                               unsigned short* __restrict__ Woutl) {
    int idx = blockIdx.x * 256 + threadIdx.x;
    if (idx >= 832 * 128) return;
    int col = idx >> 7;
    int k   = idx & 127;
    if (col < 128) {
        Wvh[col * 128 + k] = f2bf(Wv[k * 128 + col]);
    } else if (col < 512) {
        int c = col - 128;
        Woa[c * 128 + k] = f2bf(Wo[k * 384 + c]);
    } else if (col < 704) {
        int c = col - 512;
        Woa[(384 + c) * 128 + k] = f2bf(Wa[k * 192 + c]);
    } else {
        int c = col - 704;
        float v = Wout[k * 128 + c];
        unsigned short h = f2bf(v);
        Wouth[c * 128 + k] = h;
        Woutl[c * 128 + k] = f2bf(v - bf2f(h));
    }
}

// ---- (B,128,HW) -> x rows (B*LQ,128) bf16 ----
__global__ __launch_bounds__(256) void transpose_k(const float* __restrict__ fm,
                                                   unsigned short* __restrict__ xh,
                                                   int HW, int qstart) {
    __shared__ float tile[32][33];
    const int p0 = blockIdx.x * 32;
    const int c0 = blockIdx.y * 32;
    const int b  = blockIdx.z;
    const int tx = threadIdx.x;  // 32
    const int ty = threadIdx.y;  // 8
    const float* src = fm + ((size_t)(b * DM + c0)) * HW + p0;
#pragma unroll
    for (int k = 0; k < 32; k += 8)
        tile[ty + k][tx] = src[(size_t)(ty + k) * HW + tx];
    __syncthreads();
    const size_t dbase = ((size_t)(b * LQ + qstart + p0)) * DM + c0;
#pragma unroll
    for (int k = 0; k < 32; k += 8)
        xh[dbase + (size_t)(ty + k) * DM + tx] = f2bf(tile[tx][ty + k]);
}

// ---- value = x @ W_val + b_val (bf16 MFMA), repack to head-major valh ----
// valh layout: [(h*8 + b) * LQ + pos] * 8 channels (bf16), 16 B per (h,b,pos)
__global__ __launch_bounds__(256) void value_proj_mfma(const unsigned short* __restrict__ xh,
                                                       const unsigned short* __restrict__ Wvh,
                                                       const float* __restrict__ b_val,
                                                       unsigned short* __restrict__ valh) {
    __shared__ unsigned short vs[64][136];
    const int t = threadIdx.x;
    const int wv = t >> 6;
    const int lane = t & 63;
    const int m = lane & 15, quad = lane >> 4;
    const int q0 = blockIdx.x * 64 + wv * 16;

    short8 ah[4];
    const size_t arow = (size_t)(q0 + m) * DM;
#pragma unroll
    for (int kk = 0; kk < 4; ++kk)
        ah[kk] = *(const short8*)(xh + arow + kk * 32 + quad * 8);
    float4_t acc[8];
#pragma unroll
    for (int tt = 0; tt < 8; ++tt) acc[tt] = (float4_t)(0.f);
#pragma unroll
    for (int tt = 0; tt < 8; ++tt) {
        const size_t brow = (size_t)(tt * 16 + m) * DM;
#pragma unroll
        for (int kk = 0; kk < 4; ++kk) {
            short8 bh = *(const short8*)(Wvh + brow + kk * 32 + quad * 8);
            acc[tt] = __builtin_amdgcn_mfma_f32_16x16x32_bf16(ah[kk], bh, acc[tt], 0, 0, 0);
        }
    }
#pragma unroll
    for (int tt = 0; tt < 8; ++tt) {
        const int col = tt * 16 + m;
        const float bb = b_val[col];
#pragma unroll
        for (int r = 0; r < 4; ++r)
            vs[wv * 16 + quad * 4 + r][col] = f2bf(acc[tt][r] + bb);
    }
    __syncthreads();

    const int bq = blockIdx.x * 64;        // 64 queries, never spans a batch
    const int b = bq / LQ;
    const int pos0 = bq - b * LQ;
    const int h  = t >> 4;
    const int ql = t & 15;
#pragma unroll
    for (int it = 0; it < 4; ++it) {
        const int qloc = it * 16 + ql;
        uint4_t v = *(const uint4_t*)&vs[qloc][h * 8];
        *(uint4_t*)(valh + ((size_t)(h * 8 + b) * LQ + pos0 + qloc) * 8) = v;
    }
}

// ---- coef kernel: coefs = x @ Woa + bias; softmax; fp16-pack -> paramH (nt) ----
// paramH[jp][gid] packs (j=2jp, j=2jp+1) as 2 halfs; j 0..23 offsets (px), 24..35 attn
__global__ __launch_bounds__(256) void coef_k(const unsigned short* __restrict__ xh,
                                              const unsigned short* __restrict__ Woa,
                                              const float* __restrict__ b_off,
                                              const float* __restrict__ b_attn,
                                              unsigned int* __restrict__ paramH) {
    __shared__ float coef[16][16][37];  // [q][h][0..23 offs, 24..35 logits]
    const int t = threadIdx.x;
    const int wv = t >> 6;
    const int lane = t & 63;
    const int m = lane & 15, quad = lane >> 4;
    const int gq0 = blockIdx.x * 16;

    {
        short8 af[4];
        const size_t arow = (size_t)(gq0 + m) * DM;
#pragma unroll
        for (int kk = 0; kk < 4; ++kk)
            af[kk] = *(const short8*)(xh + arow + kk * 32 + quad * 8);
        float4_t acc[9];
#pragma unroll
        for (int tt = 0; tt < 9; ++tt) acc[tt] = (float4_t)(0.f);
#pragma unroll
        for (int tt = 0; tt < 9; ++tt) {
            const size_t brow = (size_t)((wv * 9 + tt) * 16 + m) * DM;
#pragma unroll
            for (int kk = 0; kk < 4; ++kk) {
                short8 bf = *(const short8*)(Woa + brow + kk * 32 + quad * 8);
                acc[tt] = __builtin_amdgcn_mfma_f32_16x16x32_bf16(af[kk], bf, acc[tt], 0, 0, 0);
            }
        }
#pragma unroll
        for (int tt = 0; tt < 9; ++tt) {
            const int col = (wv * 9 + tt) * 16 + m;
            int hc, jc;
            float bb;
            if (col < 384) { hc = col / 24; jc = col - hc * 24; bb = b_off[col]; }
            else { int cc = col - 384; hc = cc / 12; jc = 24 + cc - hc * 12; bb = b_attn[cc]; }
#pragma unroll
            for (int r = 0; r < 4; ++r)
                coef[quad * 4 + r][hc][jc] = acc[tt][r] + bb;
        }
    }
    __syncthreads();

    // softmax + fp16 pack + nt store, thread t <-> (q = t>>4, h = t&15)
    {
        const int qq = t >> 4, hh = t & 15;
        float prm[36];
#pragma unroll
        for (int j = 0; j < 36; ++j) prm[j] = coef[qq][hh][j];
        float mx = -1e30f;
#pragma unroll
        for (int k = 0; k < 12; ++k) mx = fmaxf(mx, prm[24 + k]);
        float s = 0.f;
#pragma unroll
        for (int k = 0; k < 12; ++k) {
            const float e = __expf(prm[24 + k] - mx);
            prm[24 + k] = e;
            s += e;
        }
        const float inv = 1.f / s;
#pragma unroll
        for (int k = 0; k < 12; ++k) prm[24 + k] *= inv;
        const size_t gid = (size_t)blockIdx.x * 256 + t;
#pragma unroll
        for (int jp = 0; jp < 18; ++jp)
            __builtin_nontemporal_store(packh2(prm[2 * jp], prm[2 * jp + 1]),
                                        paramH + (size_t)jp * NQH + gid);
    }
}

// ---- sampler: one thread per (q,h); no LDS, no barriers, nt param loads ----
__global__ __launch_bounds__(256, 4) void sample_k(const unsigned int* __restrict__ paramH,
                                                   const unsigned short* __restrict__ valh,
                                                   unsigned short* __restrict__ ohb) {
    const int t = threadIdx.x;
    const int gid = blockIdx.x * 256 + t;
    const int h  = gid & 15;
    const int gq = gid >> 4;
    const int b  = gq / LQ;
    const int q  = gq - b * LQ;
    int lq, p, Hq, Wq, wshift;
    q_to_level(q, lq, p, Hq, Wq, wshift);
    const float refx = ((p & (Wq - 1)) + 0.5f) / Wq;
    const float refy = ((p >> wshift) + 0.5f) / Hq;

    float prm[36];
#pragma unroll
    for (int jp = 0; jp < 18; ++jp) {
        const unsigned u = __builtin_nontemporal_load(paramH + (size_t)jp * NQH + gid);
        prm[2 * jp]     = unph_lo(u);
        prm[2 * jp + 1] = unph_hi(u);
    }

    const unsigned short* vbase = valh + ((size_t)(h * 8 + b) * LQ) * 8;
    float acc[8];
#pragma unroll
    for (int e = 0; e < 8; ++e) acc[e] = 0.f;

#pragma unroll
    for (int l = 0; l < NL; ++l) {
        const int Wl = 64 >> l;
        const int Hl = Wl;
        const int start_l = (l == 0) ? 0 : ((l == 1) ? 4096 : 5120);
        const float fxb = refx * Wl - 0.5f;
        const float fyb = refy * Hl - 0.5f;
#pragma unroll
        for (int pt = 0; pt < NP; ++pt) {
            const float ox = prm[(l * NP + pt) * 2 + 0];
            const float oy = prm[(l * NP + pt) * 2 + 1];
            const float a  = prm[24 + l * NP + pt];
            const float fx = fxb + ox;
            const float fy = fyb + oy;
            const float x0f = floorf(fx);
            const float y0f = floorf(fy);
            const int x0 = (int)x0f;
            const int y0 = (int)y0f;
            const float fx1 = fx - x0f, fy1 = fy - y0f;
            const float gx0 = (x0 >= 0 && x0 < Wl)      ? (1.f - fx1) : 0.f;
            const float gx1 = (x0 >= -1 && x0 < Wl - 1) ? fx1 : 0.f;
            const float gy0 = (y0 >= 0 && y0 < Hl)      ? (1.f - fy1) : 0.f;
            const float gy1 = (y0 >= -1 && y0 < Hl - 1) ? fy1 : 0.f;
            const int xc0 = min(max(x0, 0), Wl - 1);
            const int xc1 = min(max(x0 + 1, 0), Wl - 1);
            const int yc0 = min(max(y0, 0), Hl - 1);
            const int yc1 = min(max(y0 + 1, 0), Hl - 1);
            const int r0 = start_l + yc0 * Wl;
            const int r1 = start_l + yc1 * Wl;
            const uint4_t v00 = *(const uint4_t*)(vbase + (size_t)(r0 + xc0) * 8);
            const uint4_t v01 = *(const uint4_t*)(vbase + (size_t)(r0 + xc1) * 8);
            const uint4_t v10 = *(const uint4_t*)(vbase + (size_t)(r1 + xc0) * 8);
            const uint4_t v11 = *(const uint4_t*)(vbase + (size_t)(r1 + xc1) * 8);
            const float w00 = gx0 * gy0 * a;
            const float w01 = gx1 * gy0 * a;
            const float w10 = gx0 * gy1 * a;
            const float w11 = gx1 * gy1 * a;
#pragma unroll
            for (int dd = 0; dd < 4; ++dd) {
                acc[dd * 2 + 0] += w00 * __builtin_bit_cast(float, v00[dd] << 16)
                                +  w01 * __builtin_bit_cast(float, v01[dd] << 16)
                                +  w10 * __builtin_bit_cast(float, v10[dd] << 16)
                                +  w11 * __builtin_bit_cast(float, v11[dd] << 16);
                acc[dd * 2 + 1] += w00 * __builtin_bit_cast(float, v00[dd] & 0xffff0000u)
                                +  w01 * __builtin_bit_cast(float, v01[dd] & 0xffff0000u)
                                +  w10 * __builtin_bit_cast(float, v10[dd] & 0xffff0000u)
                                +  w11 * __builtin_bit_cast(float, v11[dd] & 0xffff0000u);
            }
        }
    }

    uint4_t uo;
#pragma unroll
    for (int e = 0; e < 4; ++e)
        uo[e] = (unsigned)f2bf(acc[2 * e]) | ((unsigned)f2bf(acc[2 * e + 1]) << 16);
    *(uint4_t*)(ohb + (size_t)gq * 128 + h * 8) = uo;
}

// ---- out projection: out = ohb @ W_out + b_out (A bf16, B hi/lo), scatter ----
__global__ __launch_bounds__(256) void outproj_k(const unsigned short* __restrict__ ohb,
                                                 const unsigned short* __restrict__ Wouth,
                                                 const unsigned short* __restrict__ Woutl,
                                                 const float* __restrict__ b_out,
                                                 float* __restrict__ out) {
    const int t = threadIdx.x;
    const int wv = t >> 6;
    const int lane = t & 63;
    const int m = lane & 15, quad = lane >> 4;
    const int q0 = blockIdx.x * 64 + wv * 16;

    short8 ah[4];
    const size_t arow = (size_t)(q0 + m) * DM;
#pragma unroll
    for (int kk = 0; kk < 4; ++kk)
        ah[kk] = *(const short8*)(ohb + arow + kk * 32 + quad * 8);

    float4_t acc[8];
#pragma unroll
    for (int tt = 0; tt < 8; ++tt) acc[tt] = (float4_t)(0.f);
#pragma unroll
    for (int tt = 0; tt < 8; ++tt) {
        const size_t brow = (size_t)(tt * 16 + m) * DM;
#pragma unroll
        for (int kk = 0; kk < 4; ++kk) {
            short8 bh = *(const short8*)(Wouth + brow + kk * 32 + quad * 8);
            short8 bl = *(const short8*)(Woutl + brow + kk * 32 + quad * 8);
            acc[tt] = __builtin_amdgcn_mfma_f32_16x16x32_bf16(ah[kk], bh, acc[tt], 0, 0, 0);
            acc[tt] = __builtin_amdgcn_mfma_f32_16x16x32_bf16(ah[kk], bl, acc[tt], 0, 0, 0);
        }
    }

    const int bq = blockIdx.x * 64;
    const int b = bq / LQ;
    const int qs = bq - b * LQ;           // 64-q tile never spans level/batch
    int lq, p0, Hq, Wq, wshift;
    q_to_level(qs, lq, p0, Hq, Wq, wshift);
    const int HW = Hq * Wq;
    const size_t lvl_base[3] = {0, 4194304, 5242880};
    float* obase = out + lvl_base[lq] + (size_t)(b * DM) * HW;
    const int posr = p0 + wv * 16 + quad * 4;
#pragma unroll
    for (int tt = 0; tt < 8; ++tt) {
        const int col = tt * 16 + m;
        const float bb = b_out[col];
        float4_t v;
#pragma unroll
        for (int r = 0; r < 4; ++r) v[r] = acc[tt][r] + bb;
        *(float4_t*)(obase + (size_t)col * HW + posr) = v;
    }
}

extern "C" void kernel_launch(void* const* d_in, const int* in_sizes, int n_in,
                              void* d_out, int out_size, void* d_ws, size_t ws_size,
                              hipStream_t stream) {
    const float* fm1    = (const float*)d_in[0];
    const float* fm2    = (const float*)d_in[1];
    const float* fm3    = (const float*)d_in[2];
    const float* W_off  = (const float*)d_in[3];
    const float* b_off  = (const float*)d_in[4];
    const float* W_attn = (const float*)d_in[5];
    const float* b_attn = (const float*)d_in[6];
    const float* W_val  = (const float*)d_in[7];
    const float* b_val  = (const float*)d_in[8];
    const float* W_out  = (const float*)d_in[9];
    const float* b_out  = (const float*)d_in[10];
    float* out = (float*)d_out;

    const size_t NQ = (size_t)8 * LQ;          // 43008
    unsigned short* xh    = (unsigned short*)d_ws;      // 11.0 MB
    unsigned short* valh  = xh + NQ * DM;               // 11.0 MB (head-major)
    unsigned short* ohb   = valh + NQ * DM;             // 11.0 MB
    unsigned short* Wvh   = ohb + NQ * DM;              // 32 KB
    unsigned short* Woa   = Wvh + 128 * 128;            // 144 KB
    unsigned short* Wouth = Woa + 576 * 128;            // 32 KB
    unsigned short* Woutl = Wouth + 128 * 128;          // 32 KB
    unsigned int* paramH  = (unsigned int*)(Woutl + 128 * 128);  // 49.5 MB

    convw_k<<<416, 256, 0, stream>>>(W_val, W_off, W_attn, W_out,
                                     Wvh, Woa, Wouth, Woutl);

    dim3 tb(32, 8);
    transpose_k<<<dim3(128, 4, 8), tb, 0, stream>>>(fm1, xh, 4096, 0);
    transpose_k<<<dim3(32, 4, 8), tb, 0, stream>>>(fm2, xh, 1024, 4096);
    transpose_k<<<dim3(8, 4, 8), tb, 0, stream>>>(fm3, xh, 256, 5120);

    value_proj_mfma<<<672, 256, 0, stream>>>(xh, Wvh, b_val, valh);

    coef_k<<<2688, 256, 0, stream>>>(xh, Woa, b_off, b_attn, paramH);

    sample_k<<<2688, 256, 0, stream>>>(paramH, valh, ohb);

    outproj_k<<<672, 256, 0, stream>>>(ohb, Wouth, Woutl, b_out, out);
}